// Round 14
// baseline (834.017 us; speedup 1.0000x reference)
//
#include <hip/hip_runtime.h>
#include <hip/hip_fp16.h>
#include <math.h>
#include <stdint.h>

#define N_NODES 50000
#define N_EDGES 1600000
#define NFEAT 512
#define NHID 256
#define NCLASS 40
#define MPAD 50048        // 391 * 128
#define NPART 8
#define PEDGE 200000      // N_EDGES / NPART (edge-balanced rank octants)
#define PCAP 212992
#define EPB2 1024
#define NBLK 196          // ceil(N_NODES/256) blocks for counting sort
#define SLICE_STRIDE ((size_t)MPAD * 32)   // f16 elems per 32-feature slice
#define CEV_CAP 6144      // staged cev entries per block (24KB LDS)
#define R40 48            // rows per block in spmm40
#define HQ 4              // node quarters for LDS hist
#define HC 16             // edge chunks for LDS hist
#define QNODES 12500      // nodes per quarter
#define QWORDS 6250       // packed u16 words per quarter
#define HEDGE (N_EDGES / HC)

typedef _Float16 half8 __attribute__((ext_vector_type(8)));
typedef float floatx4 __attribute__((ext_vector_type(4)));

__device__ __forceinline__ void gload_lds16(const void* g, void* l) {
    __builtin_amdgcn_global_load_lds((const __attribute__((address_space(1))) void*)g,
                                     (__attribute__((address_space(3))) void*)l, 16, 0, 0);
}

__device__ __forceinline__ float cev_val(unsigned ev) {
    return (float)__builtin_bit_cast(_Float16, (unsigned short)(ev >> 16));
}

// ---------------------------------------------------------------- misc

__global__ void zero_i32(int* __restrict__ p, int n) {
    int i = blockIdx.x * blockDim.x + threadIdx.x;
    if (i < n) p[i] = 0;
}

// ---------------------------------------------------------------- hist via LDS (no global atomics)
// grid HQ*HC blocks: quarter q = b>>4, chunk c = b&15. Packed u16 counts.

__global__ __launch_bounds__(256) void hist_q_kernel(const int* __restrict__ edst,
                                                     unsigned* __restrict__ ph) {
    __shared__ unsigned h32[QWORDS];
    const int q = blockIdx.x >> 4;
    const int c = blockIdx.x & 15;
    const int qbase = q * QNODES;
    const int tid = threadIdx.x;
    for (int w = tid; w < QWORDS; w += 256) h32[w] = 0;
    __syncthreads();
    const int base = c * HEDGE;
    for (int i = tid; i < HEDGE; i += 256) {
        unsigned local = (unsigned)(edst[base + i] - qbase);
        if (local < QNODES)
            atomicAdd(&h32[local >> 1], 1u << ((local & 1) << 4));
    }
    __syncthreads();
    unsigned* dst = ph + (size_t)blockIdx.x * QWORDS;
    for (int w = tid; w < QWORDS; w += 256) dst[w] = h32[w];
}

__global__ __launch_bounds__(256) void merge_hist_kernel(const unsigned* __restrict__ ph,
                                                         int* __restrict__ cnt) {
    int t = blockIdx.x * 256 + threadIdx.x;
    if (t >= HQ * QWORDS) return;
    int q = t / QWORDS;
    int wl = t - q * QWORDS;
    unsigned sum = 0;
    #pragma unroll
    for (int c = 0; c < HC; ++c)
        sum += ph[(size_t)(q * HC + c) * QWORDS + wl];
    int node = q * QNODES + wl * 2;
    cnt[node] = (int)(sum & 0xFFFF);
    cnt[node + 1] = (int)(sum >> 16);
}

// exclusive scan, 1 block, 4 elems/thread, shfl-based
__global__ __launch_bounds__(1024) void exscan4_kernel(const int* __restrict__ cnt,
                                                       int* __restrict__ rowptr,
                                                       int* __restrict__ cursor, int n) {
    __shared__ int wsum[16];
    __shared__ int carry_s;
    const int tid = threadIdx.x;
    const int lane = tid & 63;
    const int wid = tid >> 6;
    if (tid == 0) carry_s = 0;
    __syncthreads();
    for (int base = 0; base < n; base += 4096) {
        int i0 = base + tid * 4;
        int4 v = make_int4(0, 0, 0, 0);
        if (i0 + 3 < n) {
            v = *(const int4*)(cnt + i0);
        } else {
            if (i0 + 0 < n) v.x = cnt[i0 + 0];
            if (i0 + 1 < n) v.y = cnt[i0 + 1];
            if (i0 + 2 < n) v.z = cnt[i0 + 2];
        }
        int s = v.x + v.y + v.z + v.w;
        int sc = s;
        #pragma unroll
        for (int off = 1; off < 64; off <<= 1) {
            int t = __shfl_up(sc, off);
            if (lane >= off) sc += t;
        }
        if (lane == 63) wsum[wid] = sc;
        __syncthreads();
        if (wid == 0) {
            int ws = (lane < 16) ? wsum[lane] : 0;
            #pragma unroll
            for (int off = 1; off < 16; off <<= 1) {
                int t = __shfl_up(ws, off);
                if (lane >= off) ws += t;
            }
            if (lane < 16) wsum[lane] = ws;
        }
        __syncthreads();
        int ex = carry_s + (wid ? wsum[wid - 1] : 0) + sc - s;
        int p0 = ex, p1 = ex + v.x, p2 = p1 + v.y, p3 = p2 + v.z;
        if (i0 + 0 < n) { rowptr[i0 + 0] = p0; if (cursor) cursor[i0 + 0] = p0; }
        if (i0 + 1 < n) { rowptr[i0 + 1] = p1; if (cursor) cursor[i0 + 1] = p1; }
        if (i0 + 2 < n) { rowptr[i0 + 2] = p2; if (cursor) cursor[i0 + 2] = p2; }
        if (i0 + 3 < n) { rowptr[i0 + 3] = p3; if (cursor) cursor[i0 + 3] = p3; }
        __syncthreads();
        if (tid == 0) carry_s += wsum[15];
        __syncthreads();
    }
    if (tid == 0) rowptr[n] = carry_s;
}

// gather variant: scans cnt[order[i]] -> rowptr/cursor over SORTED positions
__global__ __launch_bounds__(1024) void exscan4g_kernel(const int* __restrict__ cnt,
                                                        const int* __restrict__ order,
                                                        int* __restrict__ rowptr,
                                                        int* __restrict__ cursor, int n) {
    __shared__ int wsum[16];
    __shared__ int carry_s;
    const int tid = threadIdx.x;
    const int lane = tid & 63;
    const int wid = tid >> 6;
    if (tid == 0) carry_s = 0;
    __syncthreads();
    for (int base = 0; base < n; base += 4096) {
        int i0 = base + tid * 4;
        int4 v = make_int4(0, 0, 0, 0);
        if (i0 + 0 < n) v.x = cnt[order[i0 + 0]];
        if (i0 + 1 < n) v.y = cnt[order[i0 + 1]];
        if (i0 + 2 < n) v.z = cnt[order[i0 + 2]];
        if (i0 + 3 < n) v.w = cnt[order[i0 + 3]];
        int s = v.x + v.y + v.z + v.w;
        int sc = s;
        #pragma unroll
        for (int off = 1; off < 64; off <<= 1) {
            int t = __shfl_up(sc, off);
            if (lane >= off) sc += t;
        }
        if (lane == 63) wsum[wid] = sc;
        __syncthreads();
        if (wid == 0) {
            int ws = (lane < 16) ? wsum[lane] : 0;
            #pragma unroll
            for (int off = 1; off < 16; off <<= 1) {
                int t = __shfl_up(ws, off);
                if (lane >= off) ws += t;
            }
            if (lane < 16) wsum[lane] = ws;
        }
        __syncthreads();
        int ex = carry_s + (wid ? wsum[wid - 1] : 0) + sc - s;
        int p0 = ex, p1 = ex + v.x, p2 = p1 + v.y, p3 = p2 + v.z;
        if (i0 + 0 < n) { rowptr[i0 + 0] = p0; cursor[i0 + 0] = p0; }
        if (i0 + 1 < n) { rowptr[i0 + 1] = p1; cursor[i0 + 1] = p1; }
        if (i0 + 2 < n) { rowptr[i0 + 2] = p2; cursor[i0 + 2] = p2; }
        if (i0 + 3 < n) { rowptr[i0 + 3] = p3; cursor[i0 + 3] = p3; }
        __syncthreads();
        if (tid == 0) carry_s += wsum[15];
        __syncthreads();
    }
    if (tid == 0) rowptr[n] = carry_s;
}

// ---------------------------------------------------------------- counting sort by degree (LDS-aggregated)
// bin = 255 - min(deg,255): DESCENDING degree order

__global__ __launch_bounds__(256) void sort_hist_kernel(const int* __restrict__ cnt,
                                                        int* __restrict__ gh) {
    __shared__ int lbin[256];
    int t = threadIdx.x;
    lbin[t] = 0;
    __syncthreads();
    int i = blockIdx.x * 256 + t;
    if (i < N_NODES) atomicAdd(&lbin[255 - min(cnt[i], 255)], 1);
    __syncthreads();
    gh[t * NBLK + blockIdx.x] = lbin[t];
}

__global__ __launch_bounds__(256) void sort_scatter_kernel(const int* __restrict__ cnt,
                                                           const int* __restrict__ ghx,
                                                           int* __restrict__ order,
                                                           int* __restrict__ rank) {
    __shared__ int lbase[256], lcnt2[256];
    int t = threadIdx.x;
    lbase[t] = ghx[t * NBLK + blockIdx.x];
    lcnt2[t] = 0;
    __syncthreads();
    int i = blockIdx.x * 256 + t;
    if (i < N_NODES) {
        int bin = 255 - min(cnt[i], 255);
        int my = atomicAdd(&lcnt2[bin], 1);
        int pos = lbase[bin] + my;
        order[pos] = i;
        rank[i] = pos;
    }
}

// ---------------------------------------------------------------- octant / sub-chunk bounds
// rb[o]: first rank r with rowptr[r] >= o*PEDGE. sub_lo[b] row bounds for 64 subs;
// eb[b] = rowptr[sub_lo[b]] edge bases (exact plistC layout).

__global__ __launch_bounds__(64) void oct_bounds_kernel(const int* __restrict__ rowptr,
                                                        int* __restrict__ rb,
                                                        int* __restrict__ sub_lo,
                                                        int* __restrict__ eb) {
    __shared__ int rbl[9];
    int lane = threadIdx.x;
    if (lane <= 8) {
        int v;
        if (lane == 0) v = 0;
        else if (lane == 8) v = N_NODES;
        else {
            int target = lane * PEDGE;
            int lo = 0, hi = N_NODES;
            while (lo < hi) {
                int mid = (lo + hi) >> 1;
                if (rowptr[mid] >= target) hi = mid; else lo = mid + 1;
            }
            v = lo;
        }
        rb[lane] = v;
        rbl[lane] = v;
    }
    __syncthreads();
    // 64 sub-chunks
    {
        int b = lane;
        int o = b >> 3, j = b & 7;
        int rbo = rbl[o];
        int rows = rbl[o + 1] - rbo;
        int rchunk = (rows + 7) >> 3;
        int lo = min(rbo + j * rchunk, rbl[o + 1]);
        sub_lo[b] = lo;
        eb[b] = rowptr[lo];
        if (b == 0) { sub_lo[64] = N_NODES; eb[64] = rowptr[N_NODES]; }
    }
}

// ---------------------------------------------------------------- bin2: partition edges by rank-octant
// p = rowptr[rank[dst]] / PEDGE; ballot-clustered writes; single pass.

__global__ __launch_bounds__(256) void bin2_kernel(const int* __restrict__ esrc,
                                                   const int* __restrict__ edst,
                                                   const float* __restrict__ evals,
                                                   const int* __restrict__ rank,
                                                   const int* __restrict__ rowptr,
                                                   int* __restrict__ pcount,
                                                   uint2* __restrict__ plist) {
    __shared__ int lcnt[NPART], lbase[NPART], lcur[NPART];
    const int base = blockIdx.x * EPB2;
    const int n = min(EPB2, N_EDGES - base);
    const int tid = threadIdx.x;
    const int lane = tid & 63;
    if (tid < NPART) { lcnt[tid] = 0; lcur[tid] = 0; }
    __syncthreads();
    int rd[4], rs[4], p[4];
    float v[4];
    #pragma unroll
    for (int j = 0; j < 4; ++j) {
        int i = tid + j * 256;
        bool on = i < n;
        int d = on ? edst[base + i] : 0;
        int s = on ? esrc[base + i] : 0;
        v[j] = on ? evals[base + i] : 0.f;
        rd[j] = on ? rank[d] : 0;
        rs[j] = on ? rank[s] : 0;
        p[j] = on ? (rowptr[rd[j]] / PEDGE) : NPART;
        if (on) atomicAdd(&lcnt[p[j]], 1);
    }
    __syncthreads();
    if (tid < NPART) lbase[tid] = atomicAdd(&pcount[tid], lcnt[tid]);
    __syncthreads();
    #pragma unroll
    for (int j = 0; j < 4; ++j) {
        int pp = p[j];
        int mybase = 0, myoff = 0;
        #pragma unroll
        for (int q = 0; q < NPART; ++q) {
            unsigned long long mq = __ballot(pp == q);
            int cq = __popcll(mq);
            int wbq = 0;
            if (lane == q && cq > 0) wbq = atomicAdd(&lcur[q], cq);
            wbq = __shfl(wbq, q);
            if (pp == q) {
                mybase = wbq;
                myoff = __popcll(mq & ((1ull << lane) - 1ull));
            }
        }
        if (pp < NPART) {
            plist[(size_t)pp * PCAP + lbase[pp] + mybase + myoff] =
                make_uint2(((unsigned)rd[j] << 16) | (unsigned)rs[j], __float_as_uint(v[j]));
        }
    }
}

// ---------------------------------------------------------------- bin2b: refine octant -> 8 row-subchunks
// writes into edge-exact plistC at eb[o*8+j] + running offset (LDS counters only).

__global__ __launch_bounds__(256) void bin2b_kernel(const int* __restrict__ pcountB,
                                                    const uint2* __restrict__ plistB,
                                                    const int* __restrict__ rb,
                                                    const int* __restrict__ eb,
                                                    int* __restrict__ pcountC,
                                                    uint2* __restrict__ plistC) {
    __shared__ int lcnt[NPART], lbase[NPART], lcur[NPART];
    const int o = blockIdx.x & 7;
    const int sw = blockIdx.x >> 3;
    const int nB = pcountB[o];
    const int base = sw * EPB2;
    int n = nB - base;
    if (n < 0) n = 0;
    if (n > EPB2) n = EPB2;
    const int tid = threadIdx.x;
    const int lane = tid & 63;
    if (tid < NPART) { lcnt[tid] = 0; lcur[tid] = 0; }
    __syncthreads();
    const int rbo = rb[o];
    const int rows = rb[o + 1] - rbo;
    const int rchunk = (rows + 7) >> 3;
    const uint2* lp = plistB + (size_t)o * PCAP + base;

    uint2 r[4];
    int jj[4];
    #pragma unroll
    for (int j = 0; j < 4; ++j) {
        int i = tid + j * 256;
        bool on = i < n;
        r[j] = on ? lp[i] : make_uint2(0, 0);
        int rd = (int)(r[j].x >> 16);
        jj[j] = on ? (int)((unsigned)(rd - rbo) / (unsigned)rchunk) : NPART;
        if (on) atomicAdd(&lcnt[jj[j]], 1);
    }
    __syncthreads();
    if (tid < NPART)
        lbase[tid] = eb[o * 8 + tid] + atomicAdd(&pcountC[o * 8 + tid], lcnt[tid]);
    __syncthreads();
    #pragma unroll
    for (int j = 0; j < 4; ++j) {
        int pp = jj[j];
        int mybase = 0, myoff = 0;
        #pragma unroll
        for (int q = 0; q < NPART; ++q) {
            unsigned long long mq = __ballot(pp == q);
            int cq = __popcll(mq);
            int wbq = 0;
            if (lane == q && cq > 0) wbq = atomicAdd(&lcur[q], cq);
            wbq = __shfl(wbq, q);
            if (pp == q) {
                mybase = wbq;
                myoff = __popcll(mq & ((1ull << lane) - 1ull));
            }
        }
        if (pp < NPART)
            plistC[(size_t)lbase[pp] + mybase + myoff] = r[j];
    }
}

// ---------------------------------------------------------------- pscatter3: one block per sub-chunk,
// row cursor entirely in LDS (no global atomics), single-owner cev lines.

__global__ __launch_bounds__(256) void pscatter3_kernel(const int* __restrict__ rowptr,
                                                        const int* __restrict__ sub_lo,
                                                        const uint2* __restrict__ plistC,
                                                        unsigned* __restrict__ cev) {
    __shared__ int cur[6400];
    const int b = blockIdx.x;
    const int lo = sub_lo[b];
    const int hi = sub_lo[b + 1];
    const int nr = hi - lo;
    const int tid = threadIdx.x;
    for (int i = tid; i < nr; i += 256) cur[i] = rowptr[lo + i];
    __syncthreads();
    const int ebase = rowptr[lo];
    const int n = rowptr[hi] - ebase;
    const uint2* lp = plistC + ebase;
    for (int i = tid; i < n; i += 256) {
        uint2 r = lp[i];
        int rd = (int)(r.x >> 16);
        int rs = (int)(r.x & 0xFFFF);
        int pos = atomicAdd(&cur[rd - lo], 1);
        unsigned short hb = __builtin_bit_cast(unsigned short, (_Float16)__uint_as_float(r.y));
        cev[pos] = ((unsigned)hb << 16) | (unsigned)rs;
    }
}

// ---------------------------------------------------------------- conversions

__global__ void conv_w_kernel(const float* __restrict__ W, _Float16* __restrict__ BT,
                              int K, int N, int Npad) {
    int id = blockIdx.x * blockDim.x + threadIdx.x;
    if (id >= Npad * K) return;
    int n = id / K;
    int k = id - n * K;
    BT[id] = (n < N) ? (_Float16)W[(size_t)k * N + n] : (_Float16)0.f;
}

// sequential-read x -> scatter f16 rows to sorted positions (rank). Pad rows zeroed.
__global__ __launch_bounds__(256) void conv_xs(const float* __restrict__ x,
                                               const int* __restrict__ rank,
                                               _Float16* __restrict__ xh) {
    int id = blockIdx.x * 256 + threadIdx.x;
    int node = id >> 6;                 // one row per 64 threads
    int kc = (id & 63) * 8;
    if (node >= MPAD) return;
    half8 h;
    if (node < N_NODES) {
        const float4* p = (const float4*)(x + (size_t)node * NFEAT + kc);
        float4 a = p[0], b = p[1];
        h[0] = (_Float16)a.x; h[1] = (_Float16)a.y; h[2] = (_Float16)a.z; h[3] = (_Float16)a.w;
        h[4] = (_Float16)b.x; h[5] = (_Float16)b.y; h[6] = (_Float16)b.z; h[7] = (_Float16)b.w;
        int pos = rank[node];
        __builtin_nontemporal_store(h, (half8*)(xh + (size_t)pos * NFEAT + kc));
    } else {
        #pragma unroll
        for (int j = 0; j < 8; ++j) h[j] = (_Float16)0.f;
        *(half8*)(xh + (size_t)node * NFEAT + kc) = h;
    }
}

// ---------------------------------------------------------------- GEMM #1: A = xh (f16 row-major, sorted), N=512, col-split sliced f16 out

__global__ __launch_bounds__(256, 2)
void gemm_x16(const _Float16* __restrict__ A, const _Float16* __restrict__ BT,
              const float* __restrict__ bias1,
              _Float16* __restrict__ out1, _Float16* __restrict__ out2) {
    __shared__ _Float16 As[128 * 64];
    __shared__ _Float16 Bs[128 * 64];

    const int tid = threadIdx.x;
    const int w = tid >> 6;
    const int lane = tid & 63;
    const int row0 = blockIdx.y * 128;
    const int col0 = blockIdx.x * 128;

    const int wr = w >> 1;
    const int wc = w & 1;
    const int mi = lane & 15;
    const int ksel = lane >> 4;

    const int srow = lane >> 3;
    const int scol = ((lane & 7) ^ srow) << 3;

    floatx4 acc[4][4];
    #pragma unroll
    for (int i = 0; i < 4; ++i)
        #pragma unroll
        for (int j = 0; j < 4; ++j)
            acc[i][j] = (floatx4)0.f;

    for (int k0 = 0; k0 < NFEAT; k0 += 64) {
        #pragma unroll
        for (int j = 0; j < 4; ++j) {
            int rowblk = (j * 4 + w) * 8;
            const _Float16* src = A + (size_t)(row0 + rowblk + srow) * NFEAT + k0 + scol;
            gload_lds16(src, (char*)As + rowblk * 128);
        }
        #pragma unroll
        for (int j = 0; j < 4; ++j) {
            int nblk = (j * 4 + w) * 8;
            const _Float16* src = BT + (size_t)(col0 + nblk + srow) * NFEAT + k0 + scol;
            gload_lds16(src, (char*)Bs + nblk * 128);
        }
        asm volatile("s_waitcnt vmcnt(0)" ::: "memory");
        __syncthreads();

        half8 a[2][4];
        half8 b[2][4];
        #pragma unroll
        for (int kk = 0; kk < 2; ++kk) {
            int kb = kk * 64 + (ksel << 4);
            #pragma unroll
            for (int fm = 0; fm < 4; ++fm) {
                int r = wr * 64 + fm * 16 + mi;
                int byte = kb ^ ((r & 7) << 4);
                a[kk][fm] = *(const half8*)((const char*)As + r * 128 + byte);
            }
            #pragma unroll
            for (int fn = 0; fn < 4; ++fn) {
                int n = wc * 64 + fn * 16 + mi;
                int byte = kb ^ ((n & 7) << 4);
                b[kk][fn] = *(const half8*)((const char*)Bs + n * 128 + byte);
            }
        }
        #pragma unroll
        for (int kk = 0; kk < 2; ++kk)
            #pragma unroll
            for (int fm = 0; fm < 4; ++fm)
                #pragma unroll
                for (int fn = 0; fn < 4; ++fn)
                    acc[fm][fn] = __builtin_amdgcn_mfma_f32_16x16x32_f16(
                        a[kk][fm], b[kk][fn], acc[fm][fn], 0, 0, 0);
        __syncthreads();
    }

    #pragma unroll
    for (int fm = 0; fm < 4; ++fm) {
        #pragma unroll
        for (int fn = 0; fn < 4; ++fn) {
            #pragma unroll
            for (int r = 0; r < 4; ++r) {
                int gr = row0 + wr * 64 + fm * 16 + (lane >> 4) * 4 + r;  // sorted position
                int gc = col0 + wc * 64 + fn * 16 + (lane & 15);
                if (gr < N_NODES) {
                    float v = acc[fm][fn][r];
                    if (gc < 256) {
                        out1[(size_t)(gc >> 5) * SLICE_STRIDE + (size_t)gr * 32 + (gc & 31)] =
                            (_Float16)(v + bias1[gc]);
                    } else {
                        int gc2 = gc - 256;
                        out2[(size_t)(gc2 >> 5) * SLICE_STRIDE + (size_t)gr * 32 + (gc2 & 31)] =
                            (_Float16)v;
                    }
                }
            }
        }
    }
}

// ---------------------------------------------------------------- f16 MFMA GEMM, A sliced (position-major), K-concat up to 4

template<int BN, bool OUTS>
__global__ __launch_bounds__(256, 2)
void gemm_f16(const _Float16* __restrict__ A0, const _Float16* __restrict__ A1,
              const _Float16* __restrict__ A2, const _Float16* __restrict__ A3,
              int kPerPart, int K,
              const _Float16* __restrict__ BT,
              _Float16* __restrict__ out1, int M, int N) {
    constexpr int WN = BN / 2;
    constexpr int FN = WN / 16;
    __shared__ _Float16 As[128 * 64];
    __shared__ _Float16 Bs[BN * 64];

    const int tid = threadIdx.x;
    const int w = tid >> 6;
    const int lane = tid & 63;
    const int row0 = blockIdx.y * 128;
    const int col0 = blockIdx.x * BN;

    const int wr = w >> 1;
    const int wc = w & 1;
    const int mi = lane & 15;
    const int ksel = lane >> 4;

    const int srow = lane >> 3;
    const int gsw = (lane & 7) ^ srow;

    floatx4 acc[4][FN];
    #pragma unroll
    for (int i = 0; i < 4; ++i)
        #pragma unroll
        for (int j = 0; j < FN; ++j)
            acc[i][j] = (floatx4)0.f;

    for (int k0 = 0; k0 < K; k0 += 64) {
        int part = k0 / kPerPart;
        int kloc = k0 - part * kPerPart;
        const _Float16* Ap = (part == 0) ? A0 : (part == 1) ? A1 : (part == 2) ? A2 : A3;
        int sA0 = kloc >> 5;

        #pragma unroll
        for (int j = 0; j < 4; ++j) {
            int chunk = j * 4 + w;
            int r = chunk * 8 + srow;
            const _Float16* src = Ap + (size_t)(sA0 + (gsw >> 2)) * SLICE_STRIDE
                                + (size_t)(row0 + r) * 32 + (gsw & 3) * 8;
            gload_lds16(src, (char*)As + chunk * 1024);
        }
        #pragma unroll
        for (int j = 0; j < BN / 32; ++j) {
            int nblk = (j * 4 + w) * 8;
            const _Float16* src = BT + (size_t)(col0 + nblk + srow) * K + k0 + ((lane & 7) ^ srow) * 8;
            gload_lds16(src, (char*)Bs + nblk * 128);
        }
        asm volatile("s_waitcnt vmcnt(0)" ::: "memory");
        __syncthreads();

        half8 a[2][4];
        half8 b[2][FN];
        #pragma unroll
        for (int kk = 0; kk < 2; ++kk) {
            int kb = kk * 64 + (ksel << 4);
            #pragma unroll
            for (int fm = 0; fm < 4; ++fm) {
                int r = wr * 64 + fm * 16 + mi;
                int byte = kb ^ ((r & 7) << 4);
                a[kk][fm] = *(const half8*)((const char*)As + r * 128 + byte);
            }
            #pragma unroll
            for (int fn = 0; fn < FN; ++fn) {
                int n = wc * WN + fn * 16 + mi;
                int byte = kb ^ ((n & 7) << 4);
                b[kk][fn] = *(const half8*)((const char*)Bs + n * 128 + byte);
            }
        }
        #pragma unroll
        for (int kk = 0; kk < 2; ++kk)
            #pragma unroll
            for (int fm = 0; fm < 4; ++fm)
                #pragma unroll
                for (int fn = 0; fn < FN; ++fn)
                    acc[fm][fn] = __builtin_amdgcn_mfma_f32_16x16x32_f16(
                        a[kk][fm], b[kk][fn], acc[fm][fn], 0, 0, 0);
        __syncthreads();
    }

    #pragma unroll
    for (int fm = 0; fm < 4; ++fm) {
        #pragma unroll
        for (int fn = 0; fn < FN; ++fn) {
            #pragma unroll
            for (int r = 0; r < 4; ++r) {
                int gr = row0 + wr * 64 + fm * 16 + (lane >> 4) * 4 + r;
                int gc = col0 + wc * WN + fn * 16 + (lane & 15);
                if (gr < M && gc < N) {
                    float v = acc[fm][fn][r];
                    if (OUTS) {
                        out1[(size_t)(gc >> 5) * SLICE_STRIDE + (size_t)gr * 32 + (gc & 31)] =
                            (_Float16)v;
                    } else {
                        out1[(size_t)gr * N + gc] = (_Float16)v;
                    }
                }
            }
        }
    }
}

// ---------------------------------------------------------------- sliced SpMM + bias + relu + residual

#define SPMM_EDGE_LOOP(EVSRC)                                                     \
    for (int e = 0; __any(e < deg); e += 8) {                                     \
        unsigned ev[8];                                                           \
        _Pragma("unroll")                                                         \
        for (int u = 0; u < 8; ++u) {                                             \
            int ee = e + u;                                                       \
            ev[u] = EVSRC(begs + (ee < deg ? ee : 0));                            \
        }                                                                         \
        uint4 hw[8];                                                              \
        _Pragma("unroll")                                                         \
        for (int u = 0; u < 8; ++u)                                               \
            hw[u] = *(const uint4*)(Y + (size_t)(ev[u] & 0xFFFF) * 32);           \
        _Pragma("unroll")                                                         \
        for (int u = 0; u < 8; ++u) {                                             \
            unsigned short vb = (e + u < deg) ? (unsigned short)(ev[u] >> 16)     \
                                              : (unsigned short)0;                \
            __half vh = __builtin_bit_cast(__half, vb);                           \
            __half2 vv = __half2half2(vh);                                        \
            ac0 = __hfma2(vv, __builtin_bit_cast(__half2, hw[u].x), ac0);         \
            ac1 = __hfma2(vv, __builtin_bit_cast(__half2, hw[u].y), ac1);         \
            ac2 = __hfma2(vv, __builtin_bit_cast(__half2, hw[u].z), ac2);         \
            ac3 = __hfma2(vv, __builtin_bit_cast(__half2, hw[u].w), ac3);         \
        }                                                                         \
    }

__global__ __launch_bounds__(256) void spmm_epi_sl(const int* __restrict__ rowptr,
                                                   const unsigned* __restrict__ cev,
                                                   const _Float16* __restrict__ Ysl,
                                                   const float* __restrict__ bias,
                                                   const _Float16* __restrict__ ressl,
                                                   _Float16* __restrict__ outsl) {
    __shared__ unsigned sev[CEV_CAP];
    __shared__ int srp[65];
    const int tid = threadIdx.x;
    const int w = tid >> 6;
    const int lane = tid & 63;
    const int slice = blockIdx.x & 7;
    const int rb = (blockIdx.x >> 3) * 64;

    if (tid < 65) srp[tid] = rowptr[min(rb + tid, N_NODES)];
    __syncthreads();
    const int ebase = srp[0];
    const int ecnt = srp[64] - ebase;
    const int nstage = min(ecnt, CEV_CAP);
    for (int i = tid; i < nstage; i += 256) sev[i] = cev[ebase + i];
    __syncthreads();

    const int lrow = w * 16 + (lane >> 2);
    const int rowIdx = rb + lrow;
    const int fl = (lane & 3) * 8;
    const _Float16* Y = Ysl + (size_t)slice * SLICE_STRIDE + fl;

    bool active = rowIdx < N_NODES;
    int deg = srp[lrow + 1] - srp[lrow];
    int begs = (deg > 0) ? (srp[lrow] - ebase) : 0;

    __half2 ac0 = __float2half2_rn(0.f), ac1 = ac0, ac2 = ac0, ac3 = ac0;
    if (ecnt <= CEV_CAP) {
        #define EV_LDS(i) sev[(i)]
        SPMM_EDGE_LOOP(EV_LDS)
        #undef EV_LDS
    } else {
        #define EV_GLB(i) cev[ebase + (i)]
        SPMM_EDGE_LOOP(EV_GLB)
        #undef EV_GLB
    }
    if (active) {
        int col = slice * 32 + fl;
        float4 bb0 = *(const float4*)(bias + col);
        float4 bb1 = *(const float4*)(bias + col + 4);
        size_t ro = (size_t)slice * SLICE_STRIDE + (size_t)rowIdx * 32 + fl;
        half8 rr = __builtin_nontemporal_load((const half8*)(ressl + ro));
        float2 f0 = __half22float2(ac0), f1 = __half22float2(ac1);
        float2 f2 = __half22float2(ac2), f3 = __half22float2(ac3);
        half8 o;
        o[0] = (_Float16)(fmaxf(f0.x + bb0.x, 0.f) + (float)rr[0]);
        o[1] = (_Float16)(fmaxf(f0.y + bb0.y, 0.f) + (float)rr[1]);
        o[2] = (_Float16)(fmaxf(f1.x + bb0.z, 0.f) + (float)rr[2]);
        o[3] = (_Float16)(fmaxf(f1.y + bb0.w, 0.f) + (float)rr[3]);
        o[4] = (_Float16)(fmaxf(f2.x + bb1.x, 0.f) + (float)rr[4]);
        o[5] = (_Float16)(fmaxf(f2.y + bb1.y, 0.f) + (float)rr[5]);
        o[6] = (_Float16)(fmaxf(f3.x + bb1.z, 0.f) + (float)rr[6]);
        o[7] = (_Float16)(fmaxf(f3.y + bb1.w, 0.f) + (float)rr[7]);
        __builtin_nontemporal_store(o, (half8*)(outsl + ro));
    }
}

// ---------------------------------------------------------------- SpMM D=40 + bias + log_softmax

#define SPMM40_LOOP(EVSRC)                                                        \
    for (int e = 0; __any(e < deg); e += 4) {                                     \
        unsigned ev[4];                                                           \
        _Pragma("unroll")                                                         \
        for (int u = 0; u < 4; ++u) {                                             \
            int ee = e + u;                                                       \
            ev[u] = EVSRC(begs + (ee < deg ? ee : 0));                            \
        }                                                                         \
        uint4 hw[4];                                                              \
        _Pragma("unroll")                                                         \
        for (int u = 0; u < 4; ++u)                                               \
            hw[u] = *(const uint4*)(Y5 + (size_t)(ev[u] & 0xFFFF) * NCLASS + sub * 8); \
        _Pragma("unroll")                                                         \
        for (int u = 0; u < 4; ++u) {                                             \
            float v = (e + u < deg) ? cev_val(ev[u]) : 0.f;                       \
            const _Float16* hp = (const _Float16*)&hw[u];                         \
            _Pragma("unroll")                                                     \
            for (int j = 0; j < 8; ++j) acc[j] = fmaf(v, (float)hp[j], acc[j]);   \
        }                                                                         \
    }

__global__ __launch_bounds__(256) void spmm40_lsm(const int* __restrict__ rowptr,
                                                  const int* __restrict__ order,
                                                  const unsigned* __restrict__ cev,
                                                  const _Float16* __restrict__ Y5,
                                                  const float* __restrict__ bias,
                                                  float* __restrict__ out) {
    __shared__ unsigned sev[CEV_CAP];
    __shared__ int srp[R40 + 1];
    const int tid = threadIdx.x;
    const int w = tid >> 6;
    const int lane = tid & 63;
    const int rb = blockIdx.x * R40;

    if (tid < R40 + 1) srp[tid] = rowptr[min(rb + tid, N_NODES)];
    __syncthreads();
    const int ebase = srp[0];
    const int ecnt = srp[R40] - ebase;
    const int nstage = min(ecnt, CEV_CAP);
    for (int i = tid; i < nstage; i += 256) sev[i] = cev[ebase + i];
    __syncthreads();

    const int g = lane / 5;
    const int sub = lane - g * 5;
    const int lrow = w * 12 + g;
    const int rowIdx = rb + lrow;
    bool active = (g < 12) && (rowIdx < N_NODES);
    int deg = active ? (srp[lrow + 1] - srp[lrow]) : 0;
    int begs = active ? (srp[lrow] - ebase) : 0;

    float acc[8] = {};
    if (ecnt <= CEV_CAP) {
        #define EV_LDS(i) sev[(i)]
        SPMM40_LOOP(EV_LDS)
        #undef EV_LDS
    } else {
        #define EV_GLB(i) cev[ebase + (i)]
        SPMM40_LOOP(EV_GLB)
        #undef EV_GLB
    }

    if (active) {
        float xv[8];
        #pragma unroll
        for (int j = 0; j < 8; ++j) xv[j] = acc[j] + bias[sub * 8 + j];
        float m = xv[0];
        #pragma unroll
        for (int j = 1; j < 8; ++j) m = fmaxf(m, xv[j]);
        float gm = m;
        #pragma unroll
        for (int k = 0; k < 5; ++k) gm = fmaxf(gm, __shfl(m, g * 5 + k));
        float s = 0.f;
        #pragma unroll
        for (int j = 0; j < 8; ++j) s += __expf(xv[j] - gm);
        float gs = 0.f;
        #pragma unroll
        for (int k = 0; k < 5; ++k) gs += __shfl(s, g * 5 + k);
        float ls = logf(gs);
        int row = order[rowIdx];
        float* op = out + (size_t)row * NCLASS + sub * 8;
        float4 o0, o1;
        o0.x = xv[0] - gm - ls; o0.y = xv[1] - gm - ls;
        o0.z = xv[2] - gm - ls; o0.w = xv[3] - gm - ls;
        o1.x = xv[4] - gm - ls; o1.y = xv[5] - gm - ls;
        o1.z = xv[6] - gm - ls; o1.w = xv[7] - gm - ls;
        *(float4*)(op + 0) = o0;
        *(float4*)(op + 4) = o1;
    }
}

// ---------------------------------------------------------------- launch

extern "C" void kernel_launch(void* const* d_in, const int* in_sizes, int n_in,
                              void* d_out, int out_size, void* d_ws, size_t ws_size,
                              hipStream_t stream) {
    const float* x     = (const float*)d_in[0];
    const int*   esrc  = (const int*)d_in[1];
    const int*   edst  = (const int*)d_in[2];
    const float* evals = (const float*)d_in[3];
    const float* W0 = (const float*)d_in[4];
    const float* b0 = (const float*)d_in[5];
    const float* W1 = (const float*)d_in[6];
    const float* b1 = (const float*)d_in[7];
    const float* W2 = (const float*)d_in[8];
    const float* b2 = (const float*)d_in[9];
    const float* W3 = (const float*)d_in[10];
    const float* b3 = (const float*)d_in[11];
    const float* W5 = (const float*)d_in[12];
    const float* b5 = (const float*)d_in[13];
    float* out = (float*)d_out;

    char* ws = (char*)d_ws;
    size_t off = 0;
    auto alloc = [&](size_t bytes) {
        char* p = ws + off;
        off = (off + bytes + 255) & ~(size_t)255;
        return p;
    };
    const size_t SLB = 2ull * 8 * SLICE_STRIDE;
    _Float16* xh   = (_Float16*)alloc(2ull * MPAD * NFEAT);
    _Float16* zh   = (_Float16*)alloc(SLB);
    _Float16* Yh   = (_Float16*)alloc(SLB);
    _Float16* x1h  = (_Float16*)alloc(SLB);
    _Float16* x2h  = (_Float16*)alloc(SLB);
    _Float16* x3h  = (_Float16*)alloc(SLB);
    _Float16* x4h  = (_Float16*)alloc(SLB);
    _Float16* Y5h  = (_Float16*)alloc(2ull * N_NODES * NCLASS);
    _Float16* BT01 = (_Float16*)alloc(2ull * 512 * NFEAT);
    _Float16* BT2  = (_Float16*)alloc(2ull * NHID * NHID);
    _Float16* BT3  = (_Float16*)alloc(2ull * NHID * NHID);
    _Float16* BT5  = (_Float16*)alloc(2ull * 64 * 1024);
    int* cnt    = (int*)alloc(sizeof(int) * N_NODES);
    int* pcount = (int*)alloc(sizeof(int) * (NPART + 64));
    int* pcountC = pcount + NPART;
    unsigned* ph = (unsigned*)alloc(4ull * HQ * HC * QWORDS);
    int* gh     = (int*)alloc(sizeof(int) * (NBLK * 256));
    int* ghx    = (int*)alloc(sizeof(int) * (NBLK * 256 + 1));
    int* order  = (int*)alloc(sizeof(int) * N_NODES);
    int* rank   = (int*)alloc(sizeof(int) * N_NODES);
    int* rowptr = (int*)alloc(sizeof(int) * (N_NODES + 1));
    int* cursor = (int*)alloc(sizeof(int) * N_NODES);
    int* rb     = (int*)alloc(sizeof(int) * 9);
    int* sub_lo = (int*)alloc(sizeof(int) * 65);
    int* eb     = (int*)alloc(sizeof(int) * 65);
    uint2* plistB = (uint2*)alloc(8ull * NPART * PCAP);
    uint2* plistC = (uint2*)alloc(8ull * N_EDGES);
    unsigned* cev = (unsigned*)alloc(4ull * N_EDGES + 256);
    (void)ws_size;

    // ---- CSR build: LDS hist -> degree sort -> rowptr -> octant bin -> sub bin -> LDS-cursor scatter
    zero_i32<<<1, NPART + 64, 0, stream>>>(pcount, NPART + 64);
    hist_q_kernel<<<HQ * HC, 256, 0, stream>>>(edst, ph);
    merge_hist_kernel<<<(HQ * QWORDS + 255) / 256, 256, 0, stream>>>(ph, cnt);
    sort_hist_kernel<<<NBLK, 256, 0, stream>>>(cnt, gh);
    exscan4_kernel<<<1, 1024, 0, stream>>>(gh, ghx, nullptr, NBLK * 256);
    sort_scatter_kernel<<<NBLK, 256, 0, stream>>>(cnt, ghx, order, rank);
    exscan4g_kernel<<<1, 1024, 0, stream>>>(cnt, order, rowptr, cursor, N_NODES);
    oct_bounds_kernel<<<1, 64, 0, stream>>>(rowptr, rb, sub_lo, eb);
    bin2_kernel<<<(N_EDGES + EPB2 - 1) / EPB2, 256, 0, stream>>>(esrc, edst, evals, rank, rowptr, pcount, plistB);
    bin2b_kernel<<<8 * ((PCAP + EPB2 - 1) / EPB2), 256, 0, stream>>>(pcount, plistB, rb, eb, pcountC, plistC);
    pscatter3_kernel<<<64, 256, 0, stream>>>(rowptr, sub_lo, plistC, cev);

    // ---- conversions
    conv_xs<<<MPAD / 4, 256, 0, stream>>>(x, rank, xh);
    conv_w_kernel<<<(256 * NFEAT + 255) / 256, 256, 0, stream>>>(W0, BT01, NFEAT, NHID, NHID);
    conv_w_kernel<<<(256 * NFEAT + 255) / 256, 256, 0, stream>>>(W1, BT01 + 256 * NFEAT, NFEAT, NHID, NHID);
    conv_w_kernel<<<(NHID * NHID + 255) / 256, 256, 0, stream>>>(W2, BT2, NHID, NHID, NHID);
    conv_w_kernel<<<(NHID * NHID + 255) / 256, 256, 0, stream>>>(W3, BT3, NHID, NHID, NHID);
    conv_w_kernel<<<(64 * 1024 + 255) / 256, 256, 0, stream>>>(W5, BT5, 1024, NCLASS, 64);

    const int mtiles = MPAD / 128;                  // 391
    const int spmmGrid = ((N_NODES + 63) / 64) * 8; // 782 * 8
    dim3 blk(256);

    // fused: [z | y1] = xh @ [W0 | W1]
    gemm_x16<<<dim3(4, mtiles), blk, 0, stream>>>(xh, BT01, b0, zh, Yh);
    // x1 = relu(spmm(y1)+b1) + z
    spmm_epi_sl<<<spmmGrid, blk, 0, stream>>>(rowptr, cev, Yh, b1, zh, x1h);

    // layer 2
    gemm_f16<128, true><<<dim3(2, mtiles), blk, 0, stream>>>(x1h, x1h, x1h, x1h, NHID, NHID, BT2, Yh, N_NODES, NHID);
    spmm_epi_sl<<<spmmGrid, blk, 0, stream>>>(rowptr, cev, Yh, b2, x1h, x2h);

    // layer 3 (same W2/b2)
    gemm_f16<128, true><<<dim3(2, mtiles), blk, 0, stream>>>(x2h, x2h, x2h, x2h, NHID, NHID, BT2, Yh, N_NODES, NHID);
    spmm_epi_sl<<<spmmGrid, blk, 0, stream>>>(rowptr, cev, Yh, b2, x2h, x3h);

    // layer 4
    gemm_f16<128, true><<<dim3(2, mtiles), blk, 0, stream>>>(x3h, x3h, x3h, x3h, NHID, NHID, BT3, Yh, N_NODES, NHID);
    spmm_epi_sl<<<spmmGrid, blk, 0, stream>>>(rowptr, cev, Yh, b3, x3h, x4h);

    // Y5 = concat(x4,x3,x2,x1) @ W5
    gemm_f16<64, false><<<dim3(1, mtiles), blk, 0, stream>>>(x4h, x3h, x2h, x1h, NHID, 4 * NHID, BT5, Y5h, N_NODES, NCLASS);

    // out = log_softmax(spmm(Y5) + b5)
    spmm40_lsm<<<(N_NODES + R40 - 1) / R40, blk, 0, stream>>>(rowptr, order, cev, Y5h, b5, out);
}

// Round 16
// 696.795 us; speedup vs baseline: 1.1969x; 1.1969x over previous
//
#include <hip/hip_runtime.h>
#include <hip/hip_fp16.h>
#include <math.h>
#include <stdint.h>

#define N_NODES 50000
#define N_EDGES 1600000
#define NFEAT 512
#define NHID 256
#define NCLASS 40
#define MPAD 50048        // 391 * 128
#define NPART 8
#define PEDGE 200000      // N_EDGES / NPART (edge-balanced rank octants)
#define PCAP 212992
#define EPB2 1024
#define NBLK 196          // ceil(N_NODES/256) blocks for counting sort
#define SLICE_STRIDE ((size_t)MPAD * 32)   // f16 elems per 32-feature slice
#define CEV_CAP 6144      // staged cev entries per block (24KB LDS)
#define R40 48            // rows per block in spmm40
#define HQ 4              // node quarters for LDS hist
#define HC 128            // edge chunks for LDS hist (512 blocks total)
#define QNODES 12500      // nodes per quarter
#define QWORDS 6250       // packed u16 words per quarter
#define HEDGE (N_EDGES / HC)

typedef _Float16 half8 __attribute__((ext_vector_type(8)));
typedef float floatx4 __attribute__((ext_vector_type(4)));

__device__ __forceinline__ void gload_lds16(const void* g, void* l) {
    __builtin_amdgcn_global_load_lds((const __attribute__((address_space(1))) void*)g,
                                     (__attribute__((address_space(3))) void*)l, 16, 0, 0);
}

__device__ __forceinline__ float cev_val(unsigned ev) {
    return (float)__builtin_bit_cast(_Float16, (unsigned short)(ev >> 16));
}

// ---------------------------------------------------------------- misc

__global__ void zero_i32(int* __restrict__ p, int n) {
    int i = blockIdx.x * blockDim.x + threadIdx.x;
    if (i < n) p[i] = 0;
}

// ---------------------------------------------------------------- hist via LDS (no global atomics)
// grid HQ*HC blocks: quarter q = b/HC, chunk c = b%HC. Packed u16 counts.

__global__ __launch_bounds__(256) void hist_q_kernel(const int* __restrict__ edst,
                                                     unsigned* __restrict__ ph) {
    __shared__ unsigned h32[QWORDS];
    const int q = blockIdx.x >> 7;        // / HC
    const int c = blockIdx.x & (HC - 1);
    const int qbase = q * QNODES;
    const int tid = threadIdx.x;
    for (int w = tid; w < QWORDS; w += 256) h32[w] = 0;
    __syncthreads();
    const int base = c * HEDGE;
    for (int i = tid; i < HEDGE; i += 256) {
        unsigned local = (unsigned)(edst[base + i] - qbase);
        if (local < QNODES)
            atomicAdd(&h32[local >> 1], 1u << ((local & 1) << 4));
    }
    __syncthreads();
    unsigned* dst = ph + (size_t)blockIdx.x * QWORDS;
    for (int w = tid; w < QWORDS; w += 256) dst[w] = h32[w];
}

__global__ __launch_bounds__(256) void merge_hist_kernel(const unsigned* __restrict__ ph,
                                                         int* __restrict__ cnt) {
    int t = blockIdx.x * 256 + threadIdx.x;
    if (t >= HQ * QWORDS) return;
    int q = t / QWORDS;
    int wl = t - q * QWORDS;
    unsigned sum = 0;
    #pragma unroll 16
    for (int c = 0; c < HC; ++c)
        sum += ph[(size_t)(q * HC + c) * QWORDS + wl];
    int node = q * QNODES + wl * 2;
    cnt[node] = (int)(sum & 0xFFFF);
    cnt[node + 1] = (int)(sum >> 16);
}

// exclusive scan, 1 block, 4 elems/thread, shfl-based
__global__ __launch_bounds__(1024) void exscan4_kernel(const int* __restrict__ cnt,
                                                       int* __restrict__ rowptr,
                                                       int* __restrict__ cursor, int n) {
    __shared__ int wsum[16];
    __shared__ int carry_s;
    const int tid = threadIdx.x;
    const int lane = tid & 63;
    const int wid = tid >> 6;
    if (tid == 0) carry_s = 0;
    __syncthreads();
    for (int base = 0; base < n; base += 4096) {
        int i0 = base + tid * 4;
        int4 v = make_int4(0, 0, 0, 0);
        if (i0 + 3 < n) {
            v = *(const int4*)(cnt + i0);
        } else {
            if (i0 + 0 < n) v.x = cnt[i0 + 0];
            if (i0 + 1 < n) v.y = cnt[i0 + 1];
            if (i0 + 2 < n) v.z = cnt[i0 + 2];
        }
        int s = v.x + v.y + v.z + v.w;
        int sc = s;
        #pragma unroll
        for (int off = 1; off < 64; off <<= 1) {
            int t = __shfl_up(sc, off);
            if (lane >= off) sc += t;
        }
        if (lane == 63) wsum[wid] = sc;
        __syncthreads();
        if (wid == 0) {
            int ws = (lane < 16) ? wsum[lane] : 0;
            #pragma unroll
            for (int off = 1; off < 16; off <<= 1) {
                int t = __shfl_up(ws, off);
                if (lane >= off) ws += t;
            }
            if (lane < 16) wsum[lane] = ws;
        }
        __syncthreads();
        int ex = carry_s + (wid ? wsum[wid - 1] : 0) + sc - s;
        int p0 = ex, p1 = ex + v.x, p2 = p1 + v.y, p3 = p2 + v.z;
        if (i0 + 0 < n) { rowptr[i0 + 0] = p0; if (cursor) cursor[i0 + 0] = p0; }
        if (i0 + 1 < n) { rowptr[i0 + 1] = p1; if (cursor) cursor[i0 + 1] = p1; }
        if (i0 + 2 < n) { rowptr[i0 + 2] = p2; if (cursor) cursor[i0 + 2] = p2; }
        if (i0 + 3 < n) { rowptr[i0 + 3] = p3; if (cursor) cursor[i0 + 3] = p3; }
        __syncthreads();
        if (tid == 0) carry_s += wsum[15];
        __syncthreads();
    }
    if (tid == 0) rowptr[n] = carry_s;
}

// gather variant: scans cnt[order[i]] -> rowptr/cursor over SORTED positions
__global__ __launch_bounds__(1024) void exscan4g_kernel(const int* __restrict__ cnt,
                                                        const int* __restrict__ order,
                                                        int* __restrict__ rowptr,
                                                        int* __restrict__ cursor, int n) {
    __shared__ int wsum[16];
    __shared__ int carry_s;
    const int tid = threadIdx.x;
    const int lane = tid & 63;
    const int wid = tid >> 6;
    if (tid == 0) carry_s = 0;
    __syncthreads();
    for (int base = 0; base < n; base += 4096) {
        int i0 = base + tid * 4;
        int4 v = make_int4(0, 0, 0, 0);
        if (i0 + 0 < n) v.x = cnt[order[i0 + 0]];
        if (i0 + 1 < n) v.y = cnt[order[i0 + 1]];
        if (i0 + 2 < n) v.z = cnt[order[i0 + 2]];
        if (i0 + 3 < n) v.w = cnt[order[i0 + 3]];
        int s = v.x + v.y + v.z + v.w;
        int sc = s;
        #pragma unroll
        for (int off = 1; off < 64; off <<= 1) {
            int t = __shfl_up(sc, off);
            if (lane >= off) sc += t;
        }
        if (lane == 63) wsum[wid] = sc;
        __syncthreads();
        if (wid == 0) {
            int ws = (lane < 16) ? wsum[lane] : 0;
            #pragma unroll
            for (int off = 1; off < 16; off <<= 1) {
                int t = __shfl_up(ws, off);
                if (lane >= off) ws += t;
            }
            if (lane < 16) wsum[lane] = ws;
        }
        __syncthreads();
        int ex = carry_s + (wid ? wsum[wid - 1] : 0) + sc - s;
        int p0 = ex, p1 = ex + v.x, p2 = p1 + v.y, p3 = p2 + v.z;
        if (i0 + 0 < n) { rowptr[i0 + 0] = p0; cursor[i0 + 0] = p0; }
        if (i0 + 1 < n) { rowptr[i0 + 1] = p1; cursor[i0 + 1] = p1; }
        if (i0 + 2 < n) { rowptr[i0 + 2] = p2; cursor[i0 + 2] = p2; }
        if (i0 + 3 < n) { rowptr[i0 + 3] = p3; cursor[i0 + 3] = p3; }
        __syncthreads();
        if (tid == 0) carry_s += wsum[15];
        __syncthreads();
    }
    if (tid == 0) rowptr[n] = carry_s;
}

// ---------------------------------------------------------------- counting sort by degree (LDS-aggregated)
// bin = 255 - min(deg,255): DESCENDING degree order

__global__ __launch_bounds__(256) void sort_hist_kernel(const int* __restrict__ cnt,
                                                        int* __restrict__ gh) {
    __shared__ int lbin[256];
    int t = threadIdx.x;
    lbin[t] = 0;
    __syncthreads();
    int i = blockIdx.x * 256 + t;
    if (i < N_NODES) atomicAdd(&lbin[255 - min(cnt[i], 255)], 1);
    __syncthreads();
    gh[t * NBLK + blockIdx.x] = lbin[t];
}

__global__ __launch_bounds__(256) void sort_scatter_kernel(const int* __restrict__ cnt,
                                                           const int* __restrict__ ghx,
                                                           int* __restrict__ order,
                                                           int* __restrict__ rank) {
    __shared__ int lbase[256], lcnt2[256];
    int t = threadIdx.x;
    lbase[t] = ghx[t * NBLK + blockIdx.x];
    lcnt2[t] = 0;
    __syncthreads();
    int i = blockIdx.x * 256 + t;
    if (i < N_NODES) {
        int bin = 255 - min(cnt[i], 255);
        int my = atomicAdd(&lcnt2[bin], 1);
        int pos = lbase[bin] + my;
        order[pos] = i;
        rank[i] = pos;
    }
}

// ---------------------------------------------------------------- octant / sub-chunk bounds

__global__ __launch_bounds__(64) void oct_bounds_kernel(const int* __restrict__ rowptr,
                                                        int* __restrict__ rb,
                                                        int* __restrict__ sub_lo,
                                                        int* __restrict__ eb) {
    __shared__ int rbl[9];
    int lane = threadIdx.x;
    if (lane <= 8) {
        int v;
        if (lane == 0) v = 0;
        else if (lane == 8) v = N_NODES;
        else {
            int target = lane * PEDGE;
            int lo = 0, hi = N_NODES;
            while (lo < hi) {
                int mid = (lo + hi) >> 1;
                if (rowptr[mid] >= target) hi = mid; else lo = mid + 1;
            }
            v = lo;
        }
        rb[lane] = v;
        rbl[lane] = v;
    }
    __syncthreads();
    {
        int b = lane;
        int o = b >> 3, j = b & 7;
        int rbo = rbl[o];
        int rows = rbl[o + 1] - rbo;
        int rchunk = (rows + 7) >> 3;
        int lo = min(rbo + j * rchunk, rbl[o + 1]);
        sub_lo[b] = lo;
        eb[b] = rowptr[lo];
        if (b == 0) { sub_lo[64] = N_NODES; eb[64] = rowptr[N_NODES]; }
    }
}

// ---------------------------------------------------------------- bin2: partition edges by rank-octant

__global__ __launch_bounds__(256) void bin2_kernel(const int* __restrict__ esrc,
                                                   const int* __restrict__ edst,
                                                   const float* __restrict__ evals,
                                                   const int* __restrict__ rank,
                                                   const int* __restrict__ rowptr,
                                                   int* __restrict__ pcount,
                                                   uint2* __restrict__ plist) {
    __shared__ int lcnt[NPART], lbase[NPART], lcur[NPART];
    const int base = blockIdx.x * EPB2;
    const int n = min(EPB2, N_EDGES - base);
    const int tid = threadIdx.x;
    const int lane = tid & 63;
    if (tid < NPART) { lcnt[tid] = 0; lcur[tid] = 0; }
    __syncthreads();
    int rd[4], rs[4], p[4];
    float v[4];
    #pragma unroll
    for (int j = 0; j < 4; ++j) {
        int i = tid + j * 256;
        bool on = i < n;
        int d = on ? edst[base + i] : 0;
        int s = on ? esrc[base + i] : 0;
        v[j] = on ? evals[base + i] : 0.f;
        rd[j] = on ? rank[d] : 0;
        rs[j] = on ? rank[s] : 0;
        p[j] = on ? (rowptr[rd[j]] / PEDGE) : NPART;
        if (on) atomicAdd(&lcnt[p[j]], 1);
    }
    __syncthreads();
    if (tid < NPART) lbase[tid] = atomicAdd(&pcount[tid], lcnt[tid]);
    __syncthreads();
    #pragma unroll
    for (int j = 0; j < 4; ++j) {
        int pp = p[j];
        int mybase = 0, myoff = 0;
        #pragma unroll
        for (int q = 0; q < NPART; ++q) {
            unsigned long long mq = __ballot(pp == q);
            int cq = __popcll(mq);
            int wbq = 0;
            if (lane == q && cq > 0) wbq = atomicAdd(&lcur[q], cq);
            wbq = __shfl(wbq, q);
            if (pp == q) {
                mybase = wbq;
                myoff = __popcll(mq & ((1ull << lane) - 1ull));
            }
        }
        if (pp < NPART) {
            plist[(size_t)pp * PCAP + lbase[pp] + mybase + myoff] =
                make_uint2(((unsigned)rd[j] << 16) | (unsigned)rs[j], __float_as_uint(v[j]));
        }
    }
}

// ---------------------------------------------------------------- bin2b: refine octant -> 8 row-subchunks

__global__ __launch_bounds__(256) void bin2b_kernel(const int* __restrict__ pcountB,
                                                    const uint2* __restrict__ plistB,
                                                    const int* __restrict__ rb,
                                                    const int* __restrict__ eb,
                                                    int* __restrict__ pcountC,
                                                    uint2* __restrict__ plistC) {
    __shared__ int lcnt[NPART], lbase[NPART], lcur[NPART];
    const int o = blockIdx.x & 7;
    const int sw = blockIdx.x >> 3;
    const int nB = pcountB[o];
    const int base = sw * EPB2;
    int n = nB - base;
    if (n < 0) n = 0;
    if (n > EPB2) n = EPB2;
    const int tid = threadIdx.x;
    const int lane = tid & 63;
    if (tid < NPART) { lcnt[tid] = 0; lcur[tid] = 0; }
    __syncthreads();
    const int rbo = rb[o];
    const int rows = rb[o + 1] - rbo;
    const int rchunk = (rows + 7) >> 3;
    const uint2* lp = plistB + (size_t)o * PCAP + base;

    uint2 r[4];
    int jj[4];
    #pragma unroll
    for (int j = 0; j < 4; ++j) {
        int i = tid + j * 256;
        bool on = i < n;
        r[j] = on ? lp[i] : make_uint2(0, 0);
        int rd = (int)(r[j].x >> 16);
        jj[j] = on ? (int)((unsigned)(rd - rbo) / (unsigned)rchunk) : NPART;
        if (on) atomicAdd(&lcnt[jj[j]], 1);
    }
    __syncthreads();
    if (tid < NPART)
        lbase[tid] = eb[o * 8 + tid] + atomicAdd(&pcountC[o * 8 + tid], lcnt[tid]);
    __syncthreads();
    #pragma unroll
    for (int j = 0; j < 4; ++j) {
        int pp = jj[j];
        int mybase = 0, myoff = 0;
        #pragma unroll
        for (int q = 0; q < NPART; ++q) {
            unsigned long long mq = __ballot(pp == q);
            int cq = __popcll(mq);
            int wbq = 0;
            if (lane == q && cq > 0) wbq = atomicAdd(&lcur[q], cq);
            wbq = __shfl(wbq, q);
            if (pp == q) {
                mybase = wbq;
                myoff = __popcll(mq & ((1ull << lane) - 1ull));
            }
        }
        if (pp < NPART)
            plistC[(size_t)lbase[pp] + mybase + myoff] = r[j];
    }
}

// ---------------------------------------------------------------- pscatter3: one block per sub-chunk,
// row cursor entirely in LDS (no global atomics), single-owner cev lines.

__global__ __launch_bounds__(256) void pscatter3_kernel(const int* __restrict__ rowptr,
                                                        const int* __restrict__ sub_lo,
                                                        const uint2* __restrict__ plistC,
                                                        unsigned* __restrict__ cev) {
    __shared__ int cur[6400];
    const int b = blockIdx.x;
    const int lo = sub_lo[b];
    const int hi = sub_lo[b + 1];
    const int nr = hi - lo;
    const int tid = threadIdx.x;
    for (int i = tid; i < nr; i += 256) cur[i] = rowptr[lo + i];
    __syncthreads();
    const int ebase = rowptr[lo];
    const int n = rowptr[hi] - ebase;
    const uint2* lp = plistC + ebase;
    for (int i = tid; i < n; i += 256) {
        uint2 r = lp[i];
        int rd = (int)(r.x >> 16);
        int rs = (int)(r.x & 0xFFFF);
        int pos = atomicAdd(&cur[rd - lo], 1);
        unsigned short hb = __builtin_bit_cast(unsigned short, (_Float16)__uint_as_float(r.y));
        cev[pos] = ((unsigned)hb << 16) | (unsigned)rs;
    }
}

// ---------------------------------------------------------------- conversions

__global__ void conv_w_kernel(const float* __restrict__ W, _Float16* __restrict__ BT,
                              int K, int N, int Npad) {
    int id = blockIdx.x * blockDim.x + threadIdx.x;
    if (id >= Npad * K) return;
    int n = id / K;
    int k = id - n * K;
    BT[id] = (n < N) ? (_Float16)W[(size_t)k * N + n] : (_Float16)0.f;
}

// sequential-read x -> scatter f16 rows to sorted positions (rank). Pad rows zeroed.
__global__ __launch_bounds__(256) void conv_xs(const float* __restrict__ x,
                                               const int* __restrict__ rank,
                                               _Float16* __restrict__ xh) {
    int id = blockIdx.x * 256 + threadIdx.x;
    int node = id >> 6;                 // one row per 64 threads
    int kc = (id & 63) * 8;
    if (node >= MPAD) return;
    half8 h;
    if (node < N_NODES) {
        const float4* p = (const float4*)(x + (size_t)node * NFEAT + kc);
        float4 a = p[0], b = p[1];
        h[0] = (_Float16)a.x; h[1] = (_Float16)a.y; h[2] = (_Float16)a.z; h[3] = (_Float16)a.w;
        h[4] = (_Float16)b.x; h[5] = (_Float16)b.y; h[6] = (_Float16)b.z; h[7] = (_Float16)b.w;
        int pos = rank[node];
        __builtin_nontemporal_store(h, (half8*)(xh + (size_t)pos * NFEAT + kc));
    } else {
        #pragma unroll
        for (int j = 0; j < 8; ++j) h[j] = (_Float16)0.f;
        *(half8*)(xh + (size_t)node * NFEAT + kc) = h;
    }
}

// ---------------------------------------------------------------- GEMM #1: A = xh (f16 row-major, sorted), N=512, col-split sliced f16 out

__global__ __launch_bounds__(256, 2)
void gemm_x16(const _Float16* __restrict__ A, const _Float16* __restrict__ BT,
              const float* __restrict__ bias1,
              _Float16* __restrict__ out1, _Float16* __restrict__ out2) {
    __shared__ _Float16 As[128 * 64];
    __shared__ _Float16 Bs[128 * 64];

    const int tid = threadIdx.x;
    const int w = tid >> 6;
    const int lane = tid & 63;
    const int row0 = blockIdx.y * 128;
    const int col0 = blockIdx.x * 128;

    const int wr = w >> 1;
    const int wc = w & 1;
    const int mi = lane & 15;
    const int ksel = lane >> 4;

    const int srow = lane >> 3;
    const int scol = ((lane & 7) ^ srow) << 3;

    floatx4 acc[4][4];
    #pragma unroll
    for (int i = 0; i < 4; ++i)
        #pragma unroll
        for (int j = 0; j < 4; ++j)
            acc[i][j] = (floatx4)0.f;

    for (int k0 = 0; k0 < NFEAT; k0 += 64) {
        #pragma unroll
        for (int j = 0; j < 4; ++j) {
            int rowblk = (j * 4 + w) * 8;
            const _Float16* src = A + (size_t)(row0 + rowblk + srow) * NFEAT + k0 + scol;
            gload_lds16(src, (char*)As + rowblk * 128);
        }
        #pragma unroll
        for (int j = 0; j < 4; ++j) {
            int nblk = (j * 4 + w) * 8;
            const _Float16* src = BT + (size_t)(col0 + nblk + srow) * NFEAT + k0 + scol;
            gload_lds16(src, (char*)Bs + nblk * 128);
        }
        asm volatile("s_waitcnt vmcnt(0)" ::: "memory");
        __syncthreads();

        half8 a[2][4];
        half8 b[2][4];
        #pragma unroll
        for (int kk = 0; kk < 2; ++kk) {
            int kb = kk * 64 + (ksel << 4);
            #pragma unroll
            for (int fm = 0; fm < 4; ++fm) {
                int r = wr * 64 + fm * 16 + mi;
                int byte = kb ^ ((r & 7) << 4);
                a[kk][fm] = *(const half8*)((const char*)As + r * 128 + byte);
            }
            #pragma unroll
            for (int fn = 0; fn < 4; ++fn) {
                int n = wc * 64 + fn * 16 + mi;
                int byte = kb ^ ((n & 7) << 4);
                b[kk][fn] = *(const half8*)((const char*)Bs + n * 128 + byte);
            }
        }
        #pragma unroll
        for (int kk = 0; kk < 2; ++kk)
            #pragma unroll
            for (int fm = 0; fm < 4; ++fm)
                #pragma unroll
                for (int fn = 0; fn < 4; ++fn)
                    acc[fm][fn] = __builtin_amdgcn_mfma_f32_16x16x32_f16(
                        a[kk][fm], b[kk][fn], acc[fm][fn], 0, 0, 0);
        __syncthreads();
    }

    #pragma unroll
    for (int fm = 0; fm < 4; ++fm) {
        #pragma unroll
        for (int fn = 0; fn < 4; ++fn) {
            #pragma unroll
            for (int r = 0; r < 4; ++r) {
                int gr = row0 + wr * 64 + fm * 16 + (lane >> 4) * 4 + r;  // sorted position
                int gc = col0 + wc * 64 + fn * 16 + (lane & 15);
                if (gr < N_NODES) {
                    float v = acc[fm][fn][r];
                    if (gc < 256) {
                        out1[(size_t)(gc >> 5) * SLICE_STRIDE + (size_t)gr * 32 + (gc & 31)] =
                            (_Float16)(v + bias1[gc]);
                    } else {
                        int gc2 = gc - 256;
                        out2[(size_t)(gc2 >> 5) * SLICE_STRIDE + (size_t)gr * 32 + (gc2 & 31)] =
                            (_Float16)v;
                    }
                }
            }
        }
    }
}

// ---------------------------------------------------------------- f16 MFMA GEMM, A sliced (position-major), K-concat up to 4

template<int BN, bool OUTS>
__global__ __launch_bounds__(256, 2)
void gemm_f16(const _Float16* __restrict__ A0, const _Float16* __restrict__ A1,
              const _Float16* __restrict__ A2, const _Float16* __restrict__ A3,
              int kPerPart, int K,
              const _Float16* __restrict__ BT,
              _Float16* __restrict__ out1, int M, int N) {
    constexpr int WN = BN / 2;
    constexpr int FN = WN / 16;
    __shared__ _Float16 As[128 * 64];
    __shared__ _Float16 Bs[BN * 64];

    const int tid = threadIdx.x;
    const int w = tid >> 6;
    const int lane = tid & 63;
    const int row0 = blockIdx.y * 128;
    const int col0 = blockIdx.x * BN;

    const int wr = w >> 1;
    const int wc = w & 1;
    const int mi = lane & 15;
    const int ksel = lane >> 4;

    const int srow = lane >> 3;
    const int gsw = (lane & 7) ^ srow;

    floatx4 acc[4][FN];
    #pragma unroll
    for (int i = 0; i < 4; ++i)
        #pragma unroll
        for (int j = 0; j < FN; ++j)
            acc[i][j] = (floatx4)0.f;

    for (int k0 = 0; k0 < K; k0 += 64) {
        int part = k0 / kPerPart;
        int kloc = k0 - part * kPerPart;
        const _Float16* Ap = (part == 0) ? A0 : (part == 1) ? A1 : (part == 2) ? A2 : A3;
        int sA0 = kloc >> 5;

        #pragma unroll
        for (int j = 0; j < 4; ++j) {
            int chunk = j * 4 + w;
            int r = chunk * 8 + srow;
            const _Float16* src = Ap + (size_t)(sA0 + (gsw >> 2)) * SLICE_STRIDE
                                + (size_t)(row0 + r) * 32 + (gsw & 3) * 8;
            gload_lds16(src, (char*)As + chunk * 1024);
        }
        #pragma unroll
        for (int j = 0; j < BN / 32; ++j) {
            int nblk = (j * 4 + w) * 8;
            const _Float16* src = BT + (size_t)(col0 + nblk + srow) * K + k0 + ((lane & 7) ^ srow) * 8;
            gload_lds16(src, (char*)Bs + nblk * 128);
        }
        asm volatile("s_waitcnt vmcnt(0)" ::: "memory");
        __syncthreads();

        half8 a[2][4];
        half8 b[2][FN];
        #pragma unroll
        for (int kk = 0; kk < 2; ++kk) {
            int kb = kk * 64 + (ksel << 4);
            #pragma unroll
            for (int fm = 0; fm < 4; ++fm) {
                int r = wr * 64 + fm * 16 + mi;
                int byte = kb ^ ((r & 7) << 4);
                a[kk][fm] = *(const half8*)((const char*)As + r * 128 + byte);
            }
            #pragma unroll
            for (int fn = 0; fn < FN; ++fn) {
                int n = wc * WN + fn * 16 + mi;
                int byte = kb ^ ((n & 7) << 4);
                b[kk][fn] = *(const half8*)((const char*)Bs + n * 128 + byte);
            }
        }
        #pragma unroll
        for (int kk = 0; kk < 2; ++kk)
            #pragma unroll
            for (int fm = 0; fm < 4; ++fm)
                #pragma unroll
                for (int fn = 0; fn < FN; ++fn)
                    acc[fm][fn] = __builtin_amdgcn_mfma_f32_16x16x32_f16(
                        a[kk][fm], b[kk][fn], acc[fm][fn], 0, 0, 0);
        __syncthreads();
    }

    #pragma unroll
    for (int fm = 0; fm < 4; ++fm) {
        #pragma unroll
        for (int fn = 0; fn < FN; ++fn) {
            #pragma unroll
            for (int r = 0; r < 4; ++r) {
                int gr = row0 + wr * 64 + fm * 16 + (lane >> 4) * 4 + r;
                int gc = col0 + wc * WN + fn * 16 + (lane & 15);
                if (gr < M && gc < N) {
                    float v = acc[fm][fn][r];
                    if (OUTS) {
                        out1[(size_t)(gc >> 5) * SLICE_STRIDE + (size_t)gr * 32 + (gc & 31)] =
                            (_Float16)v;
                    } else {
                        out1[(size_t)gr * N + gc] = (_Float16)v;
                    }
                }
            }
        }
    }
}

// ---------------------------------------------------------------- sliced SpMM + bias + relu + residual

#define SPMM_EDGE_LOOP(EVSRC)                                                     \
    for (int e = 0; __any(e < deg); e += 8) {                                     \
        unsigned ev[8];                                                           \
        _Pragma("unroll")                                                         \
        for (int u = 0; u < 8; ++u) {                                             \
            int ee = e + u;                                                       \
            ev[u] = EVSRC(begs + (ee < deg ? ee : 0));                            \
        }                                                                         \
        uint4 hw[8];                                                              \
        _Pragma("unroll")                                                         \
        for (int u = 0; u < 8; ++u)                                               \
            hw[u] = *(const uint4*)(Y + (size_t)(ev[u] & 0xFFFF) * 32);           \
        _Pragma("unroll")                                                         \
        for (int u = 0; u < 8; ++u) {                                             \
            unsigned short vb = (e + u < deg) ? (unsigned short)(ev[u] >> 16)     \
                                              : (unsigned short)0;                \
            __half vh = __builtin_bit_cast(__half, vb);                           \
            __half2 vv = __half2half2(vh);                                        \
            ac0 = __hfma2(vv, __builtin_bit_cast(__half2, hw[u].x), ac0);         \
            ac1 = __hfma2(vv, __builtin_bit_cast(__half2, hw[u].y), ac1);         \
            ac2 = __hfma2(vv, __builtin_bit_cast(__half2, hw[u].z), ac2);         \
            ac3 = __hfma2(vv, __builtin_bit_cast(__half2, hw[u].w), ac3);         \
        }                                                                         \
    }

__global__ __launch_bounds__(256) void spmm_epi_sl(const int* __restrict__ rowptr,
                                                   const unsigned* __restrict__ cev,
                                                   const _Float16* __restrict__ Ysl,
                                                   const float* __restrict__ bias,
                                                   const _Float16* __restrict__ ressl,
                                                   _Float16* __restrict__ outsl) {
    __shared__ unsigned sev[CEV_CAP];
    __shared__ int srp[65];
    const int tid = threadIdx.x;
    const int w = tid >> 6;
    const int lane = tid & 63;
    const int slice = blockIdx.x & 7;
    const int rb = (blockIdx.x >> 3) * 64;

    if (tid < 65) srp[tid] = rowptr[min(rb + tid, N_NODES)];
    __syncthreads();
    const int ebase = srp[0];
    const int ecnt = srp[64] - ebase;
    const int nstage = min(ecnt, CEV_CAP);
    for (int i = tid; i < nstage; i += 256) sev[i] = cev[ebase + i];
    __syncthreads();

    const int lrow = w * 16 + (lane >> 2);
    const int rowIdx = rb + lrow;
    const int fl = (lane & 3) * 8;
    const _Float16* Y = Ysl + (size_t)slice * SLICE_STRIDE + fl;

    bool active = rowIdx < N_NODES;
    int deg = srp[lrow + 1] - srp[lrow];
    int begs = (deg > 0) ? (srp[lrow] - ebase) : 0;

    __half2 ac0 = __float2half2_rn(0.f), ac1 = ac0, ac2 = ac0, ac3 = ac0;
    if (ecnt <= CEV_CAP) {
        #define EV_LDS(i) sev[(i)]
        SPMM_EDGE_LOOP(EV_LDS)
        #undef EV_LDS
    } else {
        #define EV_GLB(i) cev[ebase + (i)]
        SPMM_EDGE_LOOP(EV_GLB)
        #undef EV_GLB
    }
    if (active) {
        int col = slice * 32 + fl;
        float4 bb0 = *(const float4*)(bias + col);
        float4 bb1 = *(const float4*)(bias + col + 4);
        size_t ro = (size_t)slice * SLICE_STRIDE + (size_t)rowIdx * 32 + fl;
        half8 rr = __builtin_nontemporal_load((const half8*)(ressl + ro));
        float2 f0 = __half22float2(ac0), f1 = __half22float2(ac1);
        float2 f2 = __half22float2(ac2), f3 = __half22float2(ac3);
        half8 o;
        o[0] = (_Float16)(fmaxf(f0.x + bb0.x, 0.f) + (float)rr[0]);
        o[1] = (_Float16)(fmaxf(f0.y + bb0.y, 0.f) + (float)rr[1]);
        o[2] = (_Float16)(fmaxf(f1.x + bb0.z, 0.f) + (float)rr[2]);
        o[3] = (_Float16)(fmaxf(f1.y + bb0.w, 0.f) + (float)rr[3]);
        o[4] = (_Float16)(fmaxf(f2.x + bb1.x, 0.f) + (float)rr[4]);
        o[5] = (_Float16)(fmaxf(f2.y + bb1.y, 0.f) + (float)rr[5]);
        o[6] = (_Float16)(fmaxf(f3.x + bb1.z, 0.f) + (float)rr[6]);
        o[7] = (_Float16)(fmaxf(f3.y + bb1.w, 0.f) + (float)rr[7]);
        __builtin_nontemporal_store(o, (half8*)(outsl + ro));
    }
}

// ---------------------------------------------------------------- SpMM D=40 + bias + log_softmax

#define SPMM40_LOOP(EVSRC)                                                        \
    for (int e = 0; __any(e < deg); e += 4) {                                     \
        unsigned ev[4];                                                           \
        _Pragma("unroll")                                                         \
        for (int u = 0; u < 4; ++u) {                                             \
            int ee = e + u;                                                       \
            ev[u] = EVSRC(begs + (ee < deg ? ee : 0));                            \
        }                                                                         \
        uint4 hw[4];                                                              \
        _Pragma("unroll")                                                         \
        for (int u = 0; u < 4; ++u)                                               \
            hw[u] = *(const uint4*)(Y5 + (size_t)(ev[u] & 0xFFFF) * NCLASS + sub * 8); \
        _Pragma("unroll")                                                         \
        for (int u = 0; u < 4; ++u) {                                             \
            float v = (e + u < deg) ? cev_val(ev[u]) : 0.f;                       \
            const _Float16* hp = (const _Float16*)&hw[u];                         \
            _Pragma("unroll")                                                     \
            for (int j = 0; j < 8; ++j) acc[j] = fmaf(v, (float)hp[j], acc[j]);   \
        }                                                                         \
    }

__global__ __launch_bounds__(256) void spmm40_lsm(const int* __restrict__ rowptr,
                                                  const int* __restrict__ order,
                                                  const unsigned* __restrict__ cev,
                                                  const _Float16* __restrict__ Y5,
                                                  const float* __restrict__ bias,
                                                  float* __restrict__ out) {
    __shared__ unsigned sev[CEV_CAP];
    __shared__ int srp[R40 + 1];
    const int tid = threadIdx.x;
    const int w = tid >> 6;
    const int lane = tid & 63;
    const int rb = blockIdx.x * R40;

    if (tid < R40 + 1) srp[tid] = rowptr[min(rb + tid, N_NODES)];
    __syncthreads();
    const int ebase = srp[0];
    const int ecnt = srp[R40] - ebase;
    const int nstage = min(ecnt, CEV_CAP);
    for (int i = tid; i < nstage; i += 256) sev[i] = cev[ebase + i];
    __syncthreads();

    const int g = lane / 5;
    const int sub = lane - g * 5;
    const int lrow = w * 12 + g;
    const int rowIdx = rb + lrow;
    bool active = (g < 12) && (rowIdx < N_NODES);
    int deg = active ? (srp[lrow + 1] - srp[lrow]) : 0;
    int begs = active ? (srp[lrow] - ebase) : 0;

    float acc[8] = {};
    if (ecnt <= CEV_CAP) {
        #define EV_LDS(i) sev[(i)]
        SPMM40_LOOP(EV_LDS)
        #undef EV_LDS
    } else {
        #define EV_GLB(i) cev[ebase + (i)]
        SPMM40_LOOP(EV_GLB)
        #undef EV_GLB
    }

    if (active) {
        float xv[8];
        #pragma unroll
        for (int j = 0; j < 8; ++j) xv[j] = acc[j] + bias[sub * 8 + j];
        float m = xv[0];
        #pragma unroll
        for (int j = 1; j < 8; ++j) m = fmaxf(m, xv[j]);
        float gm = m;
        #pragma unroll
        for (int k = 0; k < 5; ++k) gm = fmaxf(gm, __shfl(m, g * 5 + k));
        float s = 0.f;
        #pragma unroll
        for (int j = 0; j < 8; ++j) s += __expf(xv[j] - gm);
        float gs = 0.f;
        #pragma unroll
        for (int k = 0; k < 5; ++k) gs += __shfl(s, g * 5 + k);
        float ls = logf(gs);
        int row = order[rowIdx];
        float* op = out + (size_t)row * NCLASS + sub * 8;
        float4 o0, o1;
        o0.x = xv[0] - gm - ls; o0.y = xv[1] - gm - ls;
        o0.z = xv[2] - gm - ls; o0.w = xv[3] - gm - ls;
        o1.x = xv[4] - gm - ls; o1.y = xv[5] - gm - ls;
        o1.z = xv[6] - gm - ls; o1.w = xv[7] - gm - ls;
        *(float4*)(op + 0) = o0;
        *(float4*)(op + 4) = o1;
    }
}

// ---------------------------------------------------------------- launch

extern "C" void kernel_launch(void* const* d_in, const int* in_sizes, int n_in,
                              void* d_out, int out_size, void* d_ws, size_t ws_size,
                              hipStream_t stream) {
    const float* x     = (const float*)d_in[0];
    const int*   esrc  = (const int*)d_in[1];
    const int*   edst  = (const int*)d_in[2];
    const float* evals = (const float*)d_in[3];
    const float* W0 = (const float*)d_in[4];
    const float* b0 = (const float*)d_in[5];
    const float* W1 = (const float*)d_in[6];
    const float* b1 = (const float*)d_in[7];
    const float* W2 = (const float*)d_in[8];
    const float* b2 = (const float*)d_in[9];
    const float* W3 = (const float*)d_in[10];
    const float* b3 = (const float*)d_in[11];
    const float* W5 = (const float*)d_in[12];
    const float* b5 = (const float*)d_in[13];
    float* out = (float*)d_out;

    char* ws = (char*)d_ws;
    size_t off = 0;
    auto alloc = [&](size_t bytes) {
        char* p = ws + off;
        off = (off + bytes + 255) & ~(size_t)255;
        return p;
    };
    const size_t SLB = 2ull * 8 * SLICE_STRIDE;
    _Float16* xh   = (_Float16*)alloc(2ull * MPAD * NFEAT);
    _Float16* zh   = (_Float16*)alloc(SLB);
    _Float16* Yh   = (_Float16*)alloc(SLB);
    _Float16* x1h  = (_Float16*)alloc(SLB);
    _Float16* x2h  = (_Float16*)alloc(SLB);
    _Float16* x3h  = (_Float16*)alloc(SLB);
    _Float16* x4h  = (_Float16*)alloc(SLB);
    _Float16* Y5h  = (_Float16*)alloc(2ull * N_NODES * NCLASS);
    _Float16* BT01 = (_Float16*)alloc(2ull * 512 * NFEAT);
    _Float16* BT2  = (_Float16*)alloc(2ull * NHID * NHID);
    _Float16* BT3  = (_Float16*)alloc(2ull * NHID * NHID);
    _Float16* BT5  = (_Float16*)alloc(2ull * 64 * 1024);
    int* cnt    = (int*)alloc(sizeof(int) * N_NODES);
    int* pcount = (int*)alloc(sizeof(int) * (NPART + 64));
    int* pcountC = pcount + NPART;
    unsigned* ph = (unsigned*)alloc(4ull * HQ * HC * QWORDS);
    int* gh     = (int*)alloc(sizeof(int) * (NBLK * 256));
    int* ghx    = (int*)alloc(sizeof(int) * (NBLK * 256 + 1));
    int* order  = (int*)alloc(sizeof(int) * N_NODES);
    int* rank   = (int*)alloc(sizeof(int) * N_NODES);
    int* rowptr = (int*)alloc(sizeof(int) * (N_NODES + 1));
    int* cursor = (int*)alloc(sizeof(int) * N_NODES);
    int* rb     = (int*)alloc(sizeof(int) * 9);
    int* sub_lo = (int*)alloc(sizeof(int) * 65);
    int* eb     = (int*)alloc(sizeof(int) * 65);
    uint2* plistB = (uint2*)alloc(8ull * NPART * PCAP);
    uint2* plistC = (uint2*)alloc(8ull * N_EDGES);
    unsigned* cev = (unsigned*)alloc(4ull * N_EDGES + 256);
    (void)ws_size;

    // ---- CSR build: LDS hist -> degree sort -> rowptr -> octant bin -> sub bin -> LDS-cursor scatter
    zero_i32<<<1, NPART + 64, 0, stream>>>(pcount, NPART + 64);
    hist_q_kernel<<<HQ * HC, 256, 0, stream>>>(edst, ph);
    merge_hist_kernel<<<(HQ * QWORDS + 255) / 256, 256, 0, stream>>>(ph, cnt);
    sort_hist_kernel<<<NBLK, 256, 0, stream>>>(cnt, gh);
    exscan4_kernel<<<1, 1024, 0, stream>>>(gh, ghx, nullptr, NBLK * 256);
    sort_scatter_kernel<<<NBLK, 256, 0, stream>>>(cnt, ghx, order, rank);
    exscan4g_kernel<<<1, 1024, 0, stream>>>(cnt, order, rowptr, cursor, N_NODES);
    oct_bounds_kernel<<<1, 64, 0, stream>>>(rowptr, rb, sub_lo, eb);
    bin2_kernel<<<(N_EDGES + EPB2 - 1) / EPB2, 256, 0, stream>>>(esrc, edst, evals, rank, rowptr, pcount, plistB);
    bin2b_kernel<<<8 * ((PCAP + EPB2 - 1) / EPB2), 256, 0, stream>>>(pcount, plistB, rb, eb, pcountC, plistC);
    pscatter3_kernel<<<64, 256, 0, stream>>>(rowptr, sub_lo, plistC, cev);

    // ---- conversions
    conv_xs<<<MPAD / 4, 256, 0, stream>>>(x, rank, xh);
    conv_w_kernel<<<(256 * NFEAT + 255) / 256, 256, 0, stream>>>(W0, BT01, NFEAT, NHID, NHID);
    conv_w_kernel<<<(256 * NFEAT + 255) / 256, 256, 0, stream>>>(W1, BT01 + 256 * NFEAT, NFEAT, NHID, NHID);
    conv_w_kernel<<<(NHID * NHID + 255) / 256, 256, 0, stream>>>(W2, BT2, NHID, NHID, NHID);
    conv_w_kernel<<<(NHID * NHID + 255) / 256, 256, 0, stream>>>(W3, BT3, NHID, NHID, NHID);
    conv_w_kernel<<<(64 * 1024 + 255) / 256, 256, 0, stream>>>(W5, BT5, 1024, NCLASS, 64);

    const int mtiles = MPAD / 128;                  // 391
    const int spmmGrid = ((N_NODES + 63) / 64) * 8; // 782 * 8
    dim3 blk(256);

    // fused: [z | y1] = xh @ [W0 | W1]
    gemm_x16<<<dim3(4, mtiles), blk, 0, stream>>>(xh, BT01, b0, zh, Yh);
    // x1 = relu(spmm(y1)+b1) + z
    spmm_epi_sl<<<spmmGrid, blk, 0, stream>>>(rowptr, cev, Yh, b1, zh, x1h);

    // layer 2
    gemm_f16<128, true><<<dim3(2, mtiles), blk, 0, stream>>>(x1h, x1h, x1h, x1h, NHID, NHID, BT2, Yh, N_NODES, NHID);
    spmm_epi_sl<<<spmmGrid, blk, 0, stream>>>(rowptr, cev, Yh, b2, x1h, x2h);

    // layer 3 (same W2/b2)
    gemm_f16<128, true><<<dim3(2, mtiles), blk, 0, stream>>>(x2h, x2h, x2h, x2h, NHID, NHID, BT2, Yh, N_NODES, NHID);
    spmm_epi_sl<<<spmmGrid, blk, 0, stream>>>(rowptr, cev, Yh, b2, x2h, x3h);

    // layer 4
    gemm_f16<128, true><<<dim3(2, mtiles), blk, 0, stream>>>(x3h, x3h, x3h, x3h, NHID, NHID, BT3, Yh, N_NODES, NHID);
    spmm_epi_sl<<<spmmGrid, blk, 0, stream>>>(rowptr, cev, Yh, b3, x3h, x4h);

    // Y5 = concat(x4,x3,x2,x1) @ W5
    gemm_f16<64, false><<<dim3(1, mtiles), blk, 0, stream>>>(x4h, x3h, x2h, x1h, NHID, 4 * NHID, BT5, Y5h, N_NODES, NCLASS);

    // out = log_softmax(spmm(Y5) + b5)
    spmm40_lsm<<<(N_NODES + R40 - 1) / R40, blk, 0, stream>>>(rowptr, order, cev, Y5h, b5, out);
}